// Round 20
// baseline (253.334 us; speedup 1.0000x reference)
//
#include <hip/hip_runtime.h>

#define HID 128
#define ELLW 64
#define FP8_SCALE 16.0f
#define FP8_INV (1.0f / 16.0f)

// ---- binned ELL build params ----
#define NBINS 400          // buckets of 256 dst nodes; supports N <= 102400
#define BINCAP 16          // LDS bin capacity
#define CHUNK_I4 512       // 2048 edges per block in pass A
#define BKCAP 5120         // global bucket capacity
#define OVF_CAP 16384

typedef _Float16 half8 __attribute__((ext_vector_type(8)));
typedef float f32x4 __attribute__((ext_vector_type(4)));
typedef float f32x2 __attribute__((ext_vector_type(2)));
struct alignas(8) H4v { _Float16 x, y, z, w; };

__device__ __forceinline__ unsigned char f32_to_fp8(float v) {
  return (unsigned char)(__builtin_amdgcn_cvt_pk_fp8_f32(v, 0.f, 0, false) & 0xff);
}

__device__ __forceinline__ void fp8x8_to_f32(uint2 u, float* o) {
  f32x2 a = __builtin_amdgcn_cvt_pk_f32_fp8(u.x, false);
  f32x2 b = __builtin_amdgcn_cvt_pk_f32_fp8(u.x, true);
  f32x2 c = __builtin_amdgcn_cvt_pk_f32_fp8(u.y, false);
  f32x2 d = __builtin_amdgcn_cvt_pk_f32_fp8(u.y, true);
  o[0] = a[0]; o[1] = a[1]; o[2] = b[0]; o[3] = b[1];
  o[4] = c[0]; o[5] = c[1]; o[6] = d[0]; o[7] = d[1];
}

__device__ __forceinline__ void fp8x8_add(uint2 u, float* acc) {
  f32x2 a = __builtin_amdgcn_cvt_pk_f32_fp8(u.x, false);
  f32x2 b = __builtin_amdgcn_cvt_pk_f32_fp8(u.x, true);
  f32x2 c = __builtin_amdgcn_cvt_pk_f32_fp8(u.y, false);
  f32x2 d = __builtin_amdgcn_cvt_pk_f32_fp8(u.y, true);
  acc[0] += a[0]; acc[1] += a[1]; acc[2] += b[0]; acc[3] += b[1];
  acc[4] += c[0]; acc[5] += c[1]; acc[6] += d[0]; acc[7] += d[1];
}

// ---------------- pass A: bin edges by dst>>8 with LDS staging ----------------

__global__ void k_zero_ints(int* p, int n) {
  int i = blockIdx.x * blockDim.x + threadIdx.x;
  if (i < n) p[i] = 0;
}

__device__ __forceinline__ void bin_one(int s, int d, int* lcnt, unsigned* bins,
                                        int* ovfn, int2* ovf) {
  int b = d >> 8;
  int p = atomicAdd(&lcnt[b], 1);
  if (p < BINCAP) bins[b * BINCAP + p] = ((unsigned)s << 8) | (unsigned)(d & 255);
  else { int q = atomicAdd(ovfn, 1); if (q < OVF_CAP) ovf[q] = make_int2(s, d); }
}

__global__ __launch_bounds__(256) void k_binA(
    const int4* __restrict__ src4, const int4* __restrict__ dst4, int E4,
    int* bkcnt, unsigned* __restrict__ bk, int* ovfn, int2* __restrict__ ovf) {
  __shared__ unsigned bins[NBINS * BINCAP];
  __shared__ int lcnt[NBINS];
  __shared__ int gbase[NBINS];
  int t = threadIdx.x;
  for (int b = t; b < NBINS; b += 256) lcnt[b] = 0;
  __syncthreads();

  int i0 = blockIdx.x * CHUNK_I4;
  int i1 = min(i0 + CHUNK_I4, E4);
  for (int i = i0 + t; i < i1; i += 256) {
    int4 d = dst4[i];
    int4 s = src4[i];
    bin_one(s.x, d.x, lcnt, bins, ovfn, ovf);
    bin_one(s.y, d.y, lcnt, bins, ovfn, ovf);
    bin_one(s.z, d.z, lcnt, bins, ovfn, ovf);
    bin_one(s.w, d.w, lcnt, bins, ovfn, ovf);
  }
  __syncthreads();

  for (int b = t; b < NBINS; b += 256) gbase[b] = atomicAdd(&bkcnt[b], min(lcnt[b], BINCAP));
  __syncthreads();

  int wid = t >> 6, lane = t & 63;
  for (int b = wid; b < NBINS; b += 4) {
    int c = min(lcnt[b], BINCAP);
    if (lane < c) {
      int off = gbase[b] + lane;
      unsigned r = bins[b * BINCAP + lane];
      if (off < BKCAP) bk[(size_t)b * BKCAP + off] = r;
      else {
        int q = atomicAdd(ovfn, 1);
        if (q < OVF_CAP) ovf[q] = make_int2((int)(r >> 8), b * 256 + (int)(r & 255));
      }
    }
  }
}

__global__ void k_tail_ovf(const int* __restrict__ src, const int* __restrict__ dst,
                           int e0, int E, int* ovfn, int2* __restrict__ ovf) {
  int e = e0 + threadIdx.x;
  if (e < E) {
    int q = atomicAdd(ovfn, 1);
    if (q < OVF_CAP) ovf[q] = make_int2(src[e], dst[e]);
  }
}

// ---------------- pass B: per-bucket ELL build + dis + x4 (fused) ----------------

__global__ __launch_bounds__(256) void k_ell_build2(
    const unsigned* __restrict__ bk, const int* __restrict__ bkcnt,
    int* __restrict__ ell, int* __restrict__ cnt,
    const float* __restrict__ x, float* __restrict__ dis,
    float4* __restrict__ x4, int N) {
  int b = blockIdx.x;
  int t = threadIdx.x;
  __shared__ int lcnt[256];
  lcnt[t] = 0;
  __syncthreads();
  int n = bkcnt[b]; if (n > BKCAP) n = BKCAP;
  const unsigned* my = bk + (size_t)b * BKCAP;
  for (int k = t; k < n; k += 256) {
    unsigned r = my[k];
    int d0 = (int)(r & 255);
    int s = (int)(r >> 8);
    int p = atomicAdd(&lcnt[d0], 1);
    if (p < ELLW) ell[(size_t)(b * 256 + d0) * ELLW + p] = s;
  }
  __syncthreads();
  int node = b * 256 + t;
  if (node < N) {
    int c = lcnt[t];
    cnt[node] = c;
    float s = rsqrtf((float)(c + 1));
    dis[node] = s;
    x4[node] = make_float4(s * x[node * 3 + 0], s * x[node * 3 + 1],
                           s * x[node * 3 + 2], 0.f);
  }
}

__global__ void k_ovf_build(const int2* __restrict__ ovf, const int* __restrict__ ovfn,
                            int* cnt, int* ell, const float* __restrict__ x,
                            float* dis, float4* x4) {
  int n = *ovfn; if (n > OVF_CAP) n = OVF_CAP;
  for (int k = threadIdx.x; k < n; k += blockDim.x) {
    int2 e = ovf[k];
    int p = atomicAdd(&cnt[e.y], 1);
    if (p < ELLW) ell[(size_t)e.y * ELLW + p] = e.x;
  }
  __syncthreads();
  for (int k = threadIdx.x; k < n; k += blockDim.x) {
    int d = ovf[k].y;
    float s = rsqrtf((float)(cnt[d] + 1));
    dis[d] = s;
    x4[d] = make_float4(s * x[d * 3 + 0], s * x[d * 3 + 1], s * x[d * 3 + 2], 0.f);
  }
}

// ---------------- edge-parallel x4 aggregation (bucket blocks, LDS atomics) --------
// z4[d] = dis[d] * (x4[d] + sum_{s in in(d)} x4[s]); bk edges only (ovf fixed later)

__global__ __launch_bounds__(256) void k_aggB(
    const unsigned* __restrict__ bk, const int* __restrict__ bkcnt,
    const float4* __restrict__ x4, const float* __restrict__ dis,
    float4* __restrict__ z4, int N) {
  __shared__ float sx[256], sy[256], sz[256];
  int b = blockIdx.x;
  int t = threadIdx.x;
  sx[t] = 0.f; sy[t] = 0.f; sz[t] = 0.f;
  __syncthreads();
  int n = bkcnt[b]; if (n > BKCAP) n = BKCAP;
  const unsigned* my = bk + (size_t)b * BKCAP;
  for (int k = t; k < n; k += 256) {
    unsigned r = my[k];
    int d0 = (int)(r & 255);
    float4 v = x4[r >> 8];
    atomicAdd(&sx[d0], v.x);
    atomicAdd(&sy[d0], v.y);
    atomicAdd(&sz[d0], v.z);
  }
  __syncthreads();
  int node = b * 256 + t;
  if (node < N) {
    float4 self = x4[node];
    float s = dis[node];
    z4[node] = make_float4(s * (sx[t] + self.x), s * (sy[t] + self.y),
                           s * (sz[t] + self.z), 0.f);
  }
}

// overflow edges' contribution to z4 (normally zero edges)
__global__ void k_ovf_agg(const int2* __restrict__ ovf, const int* __restrict__ ovfn,
                          const float* __restrict__ dis, const float4* __restrict__ x4,
                          float4* z4) {
  int n = *ovfn; if (n > OVF_CAP) n = OVF_CAP;
  for (int k = threadIdx.x; k < n; k += blockDim.x) {
    int2 e = ovf[k];
    float4 v = x4[e.x];
    float s = dis[e.y];
    float* zp = (float*)&z4[e.y];
    atomicAdd(zp + 0, s * v.x);
    atomicAdd(zp + 1, s * v.y);
    atomicAdd(zp + 2, s * v.z);
  }
}

// ---------------- fallback path (N > 102400) ----------------

__global__ void k_fill_ell1(const int* __restrict__ src, const int* __restrict__ dst,
                            int* cnt, int* ell, int E) {
  int e = blockIdx.x * blockDim.x + threadIdx.x;
  if (e < E) {
    int d = dst[e];
    int p = atomicAdd(&cnt[d], 1);
    if (p < ELLW) ell[(size_t)d * ELLW + p] = src[e];
  }
}

__global__ void k_dis_prepx(const int* __restrict__ cnt, const float* __restrict__ x,
                            float* __restrict__ dis, float4* __restrict__ x4, int N) {
  int i = blockIdx.x * blockDim.x + threadIdx.x;
  if (i >= N) return;
  float s = rsqrtf((float)(cnt[i] + 1));
  dis[i] = s;
  x4[i] = make_float4(s * x[i * 3 + 0], s * x[i * 3 + 1], s * x[i * 3 + 2], 0.f);
}

__global__ void k_agg3(const float4* __restrict__ x4, const int* __restrict__ ell,
                       const int* __restrict__ cnt, const float* __restrict__ dis,
                       float4* __restrict__ z4, int N) {
  int i = blockIdx.x * blockDim.x + threadIdx.x;
  if (i >= N) return;
  float4 a = x4[i];
  int c = cnt[i]; if (c > ELLW) c = ELLW;
  const int* row = &ell[(size_t)i * ELLW];
  int k = 0;
  for (; k + 4 <= c; k += 4) {
    int4 s4 = *(const int4*)(row + k);
    float4 v0 = x4[s4.x], v1 = x4[s4.y], v2 = x4[s4.z], v3 = x4[s4.w];
    a.x += (v0.x + v1.x) + (v2.x + v3.x);
    a.y += (v0.y + v1.y) + (v2.y + v3.y);
    a.z += (v0.z + v1.z) + (v2.z + v3.z);
  }
  for (; k < c; ++k) {
    float4 v = x4[row[k]];
    a.x += v.x; a.y += v.y; a.z += v.z;
  }
  float s = dis[i];
  z4[i] = make_float4(s * a.x, s * a.y, s * a.z, 0.f);
}

// ---------------- both weights -> fp16 transposed [n][k] ----------------

__global__ void k_prep_w16x2(const float* __restrict__ W1, const float* __restrict__ W2,
                             _Float16* __restrict__ Wt1, _Float16* __restrict__ Wt2) {
  int idx = blockIdx.x * blockDim.x + threadIdx.x;
  if (idx >= 2 * HID * HID) return;
  int which = idx >> 14;
  int r = idx & (HID * HID - 1);
  int k = r >> 7, n = r & 127;
  const float* W = which ? W2 : W1;
  _Float16* Wt = which ? Wt2 : Wt1;
  Wt[n * HID + k] = (_Float16)W[r];
}

// ---------------- slim: layer0-transform + layer1-GEMM (fp8 out, coalesced) --------

__global__ __launch_bounds__(256) void k_l01(
    const float4* __restrict__ z4, const float* __restrict__ W0,
    const float* __restrict__ b0, const _Float16* __restrict__ wt1,
    const float* __restrict__ dis, unsigned char* __restrict__ G8, int N) {
  __shared__ _Float16 hs[64][136];   // 17408 B; reused as fp8 byte buffer in epilogue
  int t = threadIdx.x;
  int base = blockIdx.x * 64;

  {
    int r = t >> 2;
    int c0 = (t & 3) * 32;
    int row = base + r;
    float4 z = make_float4(0.f, 0.f, 0.f, 0.f);
    if (row < N) z = z4[row];
#pragma unroll
    for (int c = 0; c < 32; c += 4) {
      int cc = c0 + c;
      float4 w0 = *(const float4*)&W0[0 * HID + cc];
      float4 w1 = *(const float4*)&W0[1 * HID + cc];
      float4 w2 = *(const float4*)&W0[2 * HID + cc];
      float4 bb = *(const float4*)&b0[cc];
      H4v o;
      o.x = (_Float16)fmaxf(z.x * w0.x + z.y * w1.x + z.z * w2.x + bb.x, 0.f);
      o.y = (_Float16)fmaxf(z.x * w0.y + z.y * w1.y + z.z * w2.y + bb.y, 0.f);
      o.z = (_Float16)fmaxf(z.x * w0.z + z.y * w1.z + z.z * w2.z + bb.z, 0.f);
      o.w = (_Float16)fmaxf(z.x * w0.w + z.y * w1.w + z.z * w2.w + bb.w, 0.f);
      *(H4v*)&hs[r][cc] = o;
    }
  }
  __syncthreads();

  int w = t >> 6, lane = t & 63;
  int kg = lane >> 4, ccol = lane & 15;
  int lrow = w * 16 + ccol;

  f32x4 acc[8];
#pragma unroll
  for (int nt = 0; nt < 8; ++nt) acc[nt] = (f32x4){0.f, 0.f, 0.f, 0.f};

#pragma unroll
  for (int kt = 0; kt < 4; ++kt) {
    half8 a = *(const half8*)&hs[lrow][kg * 8 + kt * 32];
#pragma unroll
    for (int nt = 0; nt < 8; ++nt) {
      half8 b = *(const half8*)(wt1 + (size_t)(nt * 16 + ccol) * HID + kg * 8 + kt * 32);
      acc[nt] = __builtin_amdgcn_mfma_f32_16x16x32_f16(a, b, acc[nt], 0, 0, 0);
    }
  }
  __syncthreads();  // MFMA reads of hs complete; safe to overwrite as byte buffer

  unsigned char* bytebuf = (unsigned char*)&hs[0][0];  // 64*144 = 9216 B
#pragma unroll
  for (int j = 0; j < 4; ++j) {
    int rl = w * 16 + kg * 4 + j;
    int row = base + rl;
    float s = dis[(row < N) ? row : (N - 1)] * FP8_SCALE;
#pragma unroll
    for (int nt = 0; nt < 8; ++nt) {
      bytebuf[rl * 144 + nt * 16 + ccol] = f32_to_fp8(s * acc[nt][j]);
    }
  }
  __syncthreads();

#pragma unroll
  for (int half = 0; half < 2; ++half) {
    int rl = (t >> 3) + half * 32;
    int seg = t & 7;
    int row = base + rl;
    if (row < N) {
      uint4 v = *(const uint4*)&bytebuf[rl * 144 + seg * 16];
      *(uint4*)&G8[(size_t)row * HID + seg * 16] = v;
    }
  }
}

// ---------------- layer-1 gather (fp8 payload, 16 lanes/row x 8B) ----------------

__global__ __launch_bounds__(256) void k_g1(
    const unsigned char* __restrict__ g8, const int* __restrict__ ell,
    const int* __restrict__ cnt, const float* __restrict__ dis,
    const float* __restrict__ b, unsigned char* __restrict__ q8, int N) {
  int tid = blockIdx.x * blockDim.x + threadIdx.x;
  int i = tid >> 4;
  int q = tid & 15;
  if (i >= N) return;
  const unsigned char* gq = g8 + q * 8;

  float acc[8];
  fp8x8_to_f32(*(const uint2*)(gq + (size_t)i * HID), acc);   // self-loop

  int c = cnt[i]; if (c > ELLW) c = ELLW;
  const int* row = ell + (size_t)i * ELLW;
  int k = 0;
  for (; k + 4 <= c; k += 4) {
    int4 s4 = *(const int4*)(row + k);
    uint2 u0 = *(const uint2*)(gq + (size_t)s4.x * HID);
    uint2 u1 = *(const uint2*)(gq + (size_t)s4.y * HID);
    uint2 u2 = *(const uint2*)(gq + (size_t)s4.z * HID);
    uint2 u3 = *(const uint2*)(gq + (size_t)s4.w * HID);
    fp8x8_add(u0, acc);
    fp8x8_add(u1, acc);
    fp8x8_add(u2, acc);
    fp8x8_add(u3, acc);
  }
  for (; k < c; ++k) {
    fp8x8_add(*(const uint2*)(gq + (size_t)row[k] * HID), acc);
  }

  float sc = dis[i];
  float sc_in = sc * FP8_INV;
  float sc_out = sc * FP8_SCALE;
  float o[8];
#pragma unroll
  for (int j = 0; j < 8; ++j) {
    float bb = b[q * 8 + j];
    o[j] = sc_out * fmaxf(sc_in * acc[j] + bb, 0.f);
  }
  int w0 = __builtin_amdgcn_cvt_pk_fp8_f32(o[0], o[1], 0, false);
  w0 = __builtin_amdgcn_cvt_pk_fp8_f32(o[2], o[3], w0, true);
  int w1 = __builtin_amdgcn_cvt_pk_fp8_f32(o[4], o[5], 0, false);
  w1 = __builtin_amdgcn_cvt_pk_fp8_f32(o[6], o[7], w1, true);
  uint2 ov; ov.x = (unsigned)w0; ov.y = (unsigned)w1;
  *(uint2*)(q8 + (size_t)i * HID + q * 8) = ov;
}

// ---------------- final: gather(q8) -> v=dis*agg -> MFMA W2 -> relu+b2 -> pool ------

__global__ __launch_bounds__(256) void k_gpool2(
    const unsigned char* __restrict__ q8, const int* __restrict__ ell,
    const int* __restrict__ cnt, const float* __restrict__ dis,
    const float* __restrict__ b2, const _Float16* __restrict__ wt2,
    const int* __restrict__ batch, float* __restrict__ pool, int N) {
  __shared__ _Float16 hs[16][136];
  int t = threadIdx.x;
  int base = blockIdx.x * 16;
  int gi = t >> 4, q = t & 15;
  int i = base + gi;

  if (i < N) {
    const unsigned char* gq = q8 + q * 8;
    float acc[8];
    fp8x8_to_f32(*(const uint2*)(gq + (size_t)i * HID), acc);

    int c = cnt[i]; if (c > ELLW) c = ELLW;
    const int* row = ell + (size_t)i * ELLW;
    int k = 0;
    for (; k + 4 <= c; k += 4) {
      int4 s4 = *(const int4*)(row + k);
      uint2 u0 = *(const uint2*)(gq + (size_t)s4.x * HID);
      uint2 u1 = *(const uint2*)(gq + (size_t)s4.y * HID);
      uint2 u2 = *(const uint2*)(gq + (size_t)s4.z * HID);
      uint2 u3 = *(const uint2*)(gq + (size_t)s4.w * HID);
      fp8x8_add(u0, acc);
      fp8x8_add(u1, acc);
      fp8x8_add(u2, acc);
      fp8x8_add(u3, acc);
    }
    for (; k < c; ++k) {
      fp8x8_add(*(const uint2*)(gq + (size_t)row[k] * HID), acc);
    }

    float sc = dis[i] * FP8_INV;
    half8 o;
#pragma unroll
    for (int j = 0; j < 8; ++j) o[j] = (_Float16)(sc * acc[j]);
    *(half8*)&hs[gi][q * 8] = o;
  } else {
    half8 zo;
#pragma unroll
    for (int j = 0; j < 8; ++j) zo[j] = (_Float16)0.f;
    *(half8*)&hs[gi][q * 8] = zo;
  }
  __syncthreads();

  int w = t >> 6, lane = t & 63;
  int kg = lane >> 4, rloc = lane & 15;
  f32x4 acc2[2];
  acc2[0] = (f32x4){0.f, 0.f, 0.f, 0.f};
  acc2[1] = (f32x4){0.f, 0.f, 0.f, 0.f};

#pragma unroll
  for (int kt = 0; kt < 4; ++kt) {
    half8 a = *(const half8*)&hs[rloc][kg * 8 + kt * 32];
#pragma unroll
    for (int ntl = 0; ntl < 2; ++ntl) {
      int n = (2 * w + ntl) * 16 + rloc;
      half8 bf = *(const half8*)(wt2 + (size_t)n * HID + kg * 8 + kt * 32);
      acc2[ntl] = __builtin_amdgcn_mfma_f32_16x16x32_f16(a, bf, acc2[ntl], 0, 0, 0);
    }
  }

  float v2[2][4];
#pragma unroll
  for (int ntl = 0; ntl < 2; ++ntl) {
    int col = (2 * w + ntl) * 16 + rloc;
    float bb = b2[col];
#pragma unroll
    for (int j = 0; j < 4; ++j) v2[ntl][j] = fmaxf(acc2[ntl][j] + bb, 0.f);
  }
  int brow[4];
#pragma unroll
  for (int j = 0; j < 4; ++j) {
    int row = base + kg * 4 + j;
    brow[j] = (row < N) ? batch[row] : -1;
  }
  int g0 = batch[base];
  int lastr = base + 15; if (lastr >= N) lastr = N - 1;
  int g1 = batch[lastr];

  for (int s = g0; s <= g1; ++s) {
#pragma unroll
    for (int ntl = 0; ntl < 2; ++ntl) {
      float p = 0.f;
#pragma unroll
      for (int j = 0; j < 4; ++j) p += (brow[j] == s) ? v2[ntl][j] : 0.f;
      p += __shfl_xor(p, 16);
      p += __shfl_xor(p, 32);
      if (kg == 0 && p != 0.f) {
        atomicAdd(&pool[s * HID + (2 * w + ntl) * 16 + rloc], p);
      }
    }
  }
}

// ---------------- MLP head ----------------

__device__ __forceinline__ int lower_bound_i(const int* __restrict__ a, int n, int v) {
  int lo = 0, hi = n;
  while (lo < hi) {
    int m = (lo + hi) >> 1;
    if (a[m] < v) lo = m + 1; else hi = m;
  }
  return lo;
}

__global__ __launch_bounds__(64) void k_mlp512(
    const float* __restrict__ pool, const int* __restrict__ batch, int N,
    const float* __restrict__ Wf1, const float* __restrict__ bf1,
    const float* __restrict__ Wf2, const float* __restrict__ bf2,
    float* __restrict__ out) {
  int g = blockIdx.x;
  int lane = threadIdx.x;
  int lo = lower_bound_i(batch, N, g);
  int hi = lower_bound_i(batch, N, g + 1);
  float inv = 1.0f / fmaxf((float)(hi - lo), 1.0f);

  __shared__ float p[128];
  p[lane] = pool[g * HID + lane] * inv;
  p[lane + 64] = pool[g * HID + 64 + lane] * inv;
  __syncthreads();

  float a = bf1[lane];
  for (int k = 0; k < 128; ++k) a += p[k] * Wf1[k * 64 + lane];
  a = fmaxf(a, 0.f);
  float prod = a * Wf2[lane];
#pragma unroll
  for (int off = 32; off; off >>= 1) prod += __shfl_down(prod, off);
  if (lane == 0) out[g] = prod + bf2[0];
}

// ---------------- launch ----------------

static inline size_t align256(size_t x) { return (x + 255) & ~(size_t)255; }

extern "C" void kernel_launch(void* const* d_in, const int* in_sizes, int n_in,
                              void* d_out, int out_size, void* d_ws, size_t ws_size,
                              hipStream_t stream) {
  const float* x = (const float*)d_in[0];
  const int* ei = (const int*)d_in[1];
  const int* batch = (const int*)d_in[2];
  const float* W0 = (const float*)d_in[3];
  const float* b0 = (const float*)d_in[4];
  const float* W1 = (const float*)d_in[5];
  const float* b1 = (const float*)d_in[6];
  const float* W2 = (const float*)d_in[7];
  const float* b2 = (const float*)d_in[8];
  const float* Wf1 = (const float*)d_in[9];
  const float* bf1 = (const float*)d_in[10];
  const float* Wf2 = (const float*)d_in[11];
  const float* bf2 = (const float*)d_in[12];
  float* out = (float*)d_out;

  const int N = in_sizes[0] / 3;
  const int E = in_sizes[1] / 2;
  const int Gn = out_size;
  const int nbuk = (N + 255) >> 8;

  const int* src = ei;
  const int* dst = ei + E;

  char* ws = (char*)d_ws;
  size_t o = 0;
  int* cnt = (int*)(ws + o); o = align256(o + (size_t)N * 4);
  float* dis = (float*)(ws + o); o = align256(o + (size_t)N * 4);
  float4* x4 = (float4*)(ws + o); o = align256(o + (size_t)N * 16);
  float4* z4 = (float4*)(ws + o); o = align256(o + (size_t)N * 16);
  int* ell = (int*)(ws + o); o = align256(o + (size_t)N * ELLW * 4);
  unsigned char* g8a = (unsigned char*)(ws + o); o = align256(o + (size_t)N * HID);
  unsigned char* q8 = (unsigned char*)(ws + o); o = align256(o + (size_t)N * HID);
  _Float16* wt1 = (_Float16*)(ws + o); o = align256(o + (size_t)HID * HID * 2);
  _Float16* wt2 = (_Float16*)(ws + o); o = align256(o + (size_t)HID * HID * 2);
  // bkcnt(+ovfn) and pool adjacent -> single zeroing launch covers both
  size_t zero_base = o;
  int* bkcnt = (int*)(ws + o); o = align256(o + (size_t)(NBINS + 1) * 4);
  int* ovfn = bkcnt + NBINS;
  float* pool = (float*)(ws + o); o = align256(o + (size_t)Gn * HID * 4);
  size_t zero_bytes = o - zero_base;
  unsigned* bk = (unsigned*)(ws + o); o = align256(o + (size_t)NBINS * BKCAP * 4);
  int2* ovf = (int2*)(ws + o); o = align256(o + (size_t)OVF_CAP * 8);

  const int BS = 256;
  int gN = (N + BS - 1) / BS;
  int gN16 = (int)(((long long)N * 16 + BS - 1) / BS);
  int gW2 = (2 * HID * HID + BS - 1) / BS;
  int zn = (int)(zero_bytes / 4);

  // ---- zero bkcnt + ovfn + pool in one launch ----
  k_zero_ints<<<(zn + BS - 1) / BS, BS, 0, stream>>>((int*)(ws + zero_base), zn);

  // ---- ELL build (+ dis + x4) + edge-parallel aggregation ----
  bool vec4ok = (E % 4 == 0) && (((uintptr_t)src & 15) == 0) && (((uintptr_t)dst & 15) == 0);
  if (nbuk <= NBINS) {
    int E4 = E / 4;
    if (E4 > 0 && vec4ok) {
      k_binA<<<(E4 + CHUNK_I4 - 1) / CHUNK_I4, 256, 0, stream>>>(
          (const int4*)src, (const int4*)dst, E4, bkcnt, bk, ovfn, ovf);
      if (E % 4) k_tail_ovf<<<1, 64, 0, stream>>>(src, dst, E4 * 4, E, ovfn, ovf);
    } else {
      k_tail_ovf<<<1, 256, 0, stream>>>(src, dst, 0, E, ovfn, ovf);
    }
    k_ell_build2<<<nbuk, 256, 0, stream>>>(bk, bkcnt, ell, cnt, x, dis, x4, N);
    k_ovf_build<<<1, 256, 0, stream>>>(ovf, ovfn, cnt, ell, x, dis, x4);
    k_aggB<<<nbuk, 256, 0, stream>>>(bk, bkcnt, x4, dis, z4, N);
    k_ovf_agg<<<1, 256, 0, stream>>>(ovf, ovfn, dis, x4, z4);
  } else {
    k_zero_ints<<<gN, BS, 0, stream>>>(cnt, N);
    k_fill_ell1<<<(E + BS - 1) / BS, BS, 0, stream>>>(src, dst, cnt, ell, E);
    k_dis_prepx<<<gN, BS, 0, stream>>>(cnt, x, dis, x4, N);
    k_agg3<<<gN, BS, 0, stream>>>(x4, ell, cnt, dis, z4, N);
  }

  // ---- weight prep ----
  k_prep_w16x2<<<gW2, BS, 0, stream>>>(W1, W2, wt1, wt2);

  // ---- slim: h0 = relu(z4@W0+b0); g8a = fp8(dis*(h0@W1)), coalesced store ----
  k_l01<<<(N + 63) / 64, 256, 0, stream>>>(z4, W0, b0, wt1, dis, g8a, N);

  // ---- gather: q8 = fp8(dis * relu(dis * (A g8a) + b1)) ----
  k_g1<<<gN16, BS, 0, stream>>>(g8a, ell, cnt, dis, b1, q8, N);

  // ---- final: gather(q8) -> v -> @W2 + b2, relu -> pool ----
  k_gpool2<<<(N + 15) / 16, 256, 0, stream>>>(q8, ell, cnt, dis, b2, wt2, batch, pool, N);

  // ---- MLP head ----
  k_mlp512<<<Gn, 64, 0, stream>>>(pool, batch, N, Wf1, bf1, Wf2, bf2, out);
}

// Round 21
// 225.002 us; speedup vs baseline: 1.1259x; 1.1259x over previous
//
#include <hip/hip_runtime.h>

#define HID 128
#define ELLW 64
#define FP8_SCALE 16.0f
#define FP8_INV (1.0f / 16.0f)

// ---- binned ELL build params ----
#define NBINS 400          // buckets of 256 dst nodes; supports N <= 102400
#define BINCAP 16          // LDS bin capacity
#define CHUNK_I4 512       // 2048 edges per block in pass A
#define BKCAP 5120         // global bucket capacity
#define OVF_CAP 16384

typedef _Float16 half8 __attribute__((ext_vector_type(8)));
typedef float f32x4 __attribute__((ext_vector_type(4)));
typedef float f32x2 __attribute__((ext_vector_type(2)));
struct alignas(8) H4v { _Float16 x, y, z, w; };

__device__ __forceinline__ unsigned char f32_to_fp8(float v) {
  return (unsigned char)(__builtin_amdgcn_cvt_pk_fp8_f32(v, 0.f, 0, false) & 0xff);
}

__device__ __forceinline__ void fp8x8_to_f32(uint2 u, float* o) {
  f32x2 a = __builtin_amdgcn_cvt_pk_f32_fp8(u.x, false);
  f32x2 b = __builtin_amdgcn_cvt_pk_f32_fp8(u.x, true);
  f32x2 c = __builtin_amdgcn_cvt_pk_f32_fp8(u.y, false);
  f32x2 d = __builtin_amdgcn_cvt_pk_f32_fp8(u.y, true);
  o[0] = a[0]; o[1] = a[1]; o[2] = b[0]; o[3] = b[1];
  o[4] = c[0]; o[5] = c[1]; o[6] = d[0]; o[7] = d[1];
}

__device__ __forceinline__ void fp8x8_add(uint2 u, float* acc) {
  f32x2 a = __builtin_amdgcn_cvt_pk_f32_fp8(u.x, false);
  f32x2 b = __builtin_amdgcn_cvt_pk_f32_fp8(u.x, true);
  f32x2 c = __builtin_amdgcn_cvt_pk_f32_fp8(u.y, false);
  f32x2 d = __builtin_amdgcn_cvt_pk_f32_fp8(u.y, true);
  acc[0] += a[0]; acc[1] += a[1]; acc[2] += b[0]; acc[3] += b[1];
  acc[4] += c[0]; acc[5] += c[1]; acc[6] += d[0]; acc[7] += d[1];
}

// ---------------- pass A: bin edges by dst>>8 with LDS staging ----------------

__global__ void k_zero_ints(int* p, int n) {
  int i = blockIdx.x * blockDim.x + threadIdx.x;
  if (i < n) p[i] = 0;
}

__device__ __forceinline__ void bin_one(int s, int d, int* lcnt, unsigned* bins,
                                        int* ovfn, int2* ovf) {
  int b = d >> 8;
  int p = atomicAdd(&lcnt[b], 1);
  if (p < BINCAP) bins[b * BINCAP + p] = ((unsigned)s << 8) | (unsigned)(d & 255);
  else { int q = atomicAdd(ovfn, 1); if (q < OVF_CAP) ovf[q] = make_int2(s, d); }
}

__global__ __launch_bounds__(256) void k_binA(
    const int4* __restrict__ src4, const int4* __restrict__ dst4, int E4,
    int* bkcnt, unsigned* __restrict__ bk, int* ovfn, int2* __restrict__ ovf) {
  __shared__ unsigned bins[NBINS * BINCAP];
  __shared__ int lcnt[NBINS];
  __shared__ int gbase[NBINS];
  int t = threadIdx.x;
  for (int b = t; b < NBINS; b += 256) lcnt[b] = 0;
  __syncthreads();

  int i0 = blockIdx.x * CHUNK_I4;
  int i1 = min(i0 + CHUNK_I4, E4);
  for (int i = i0 + t; i < i1; i += 256) {
    int4 d = dst4[i];
    int4 s = src4[i];
    bin_one(s.x, d.x, lcnt, bins, ovfn, ovf);
    bin_one(s.y, d.y, lcnt, bins, ovfn, ovf);
    bin_one(s.z, d.z, lcnt, bins, ovfn, ovf);
    bin_one(s.w, d.w, lcnt, bins, ovfn, ovf);
  }
  __syncthreads();

  for (int b = t; b < NBINS; b += 256) gbase[b] = atomicAdd(&bkcnt[b], min(lcnt[b], BINCAP));
  __syncthreads();

  int wid = t >> 6, lane = t & 63;
  for (int b = wid; b < NBINS; b += 4) {
    int c = min(lcnt[b], BINCAP);
    if (lane < c) {
      int off = gbase[b] + lane;
      unsigned r = bins[b * BINCAP + lane];
      if (off < BKCAP) bk[(size_t)b * BKCAP + off] = r;
      else {
        int q = atomicAdd(ovfn, 1);
        if (q < OVF_CAP) ovf[q] = make_int2((int)(r >> 8), b * 256 + (int)(r & 255));
      }
    }
  }
}

__global__ void k_tail_ovf(const int* __restrict__ src, const int* __restrict__ dst,
                           int e0, int E, int* ovfn, int2* __restrict__ ovf) {
  int e = e0 + threadIdx.x;
  if (e < E) {
    int q = atomicAdd(ovfn, 1);
    if (q < OVF_CAP) ovf[q] = make_int2(src[e], dst[e]);
  }
}

// ---------------- pass B: per-bucket ELL build + dis + x4 (fused) ----------------

__global__ __launch_bounds__(256) void k_ell_build2(
    const unsigned* __restrict__ bk, const int* __restrict__ bkcnt,
    int* __restrict__ ell, int* __restrict__ cnt,
    const float* __restrict__ x, float* __restrict__ dis,
    float4* __restrict__ x4, int N) {
  int b = blockIdx.x;
  int t = threadIdx.x;
  __shared__ int lcnt[256];
  lcnt[t] = 0;
  __syncthreads();
  int n = bkcnt[b]; if (n > BKCAP) n = BKCAP;
  const unsigned* my = bk + (size_t)b * BKCAP;
  for (int k = t; k < n; k += 256) {
    unsigned r = my[k];
    int d0 = (int)(r & 255);
    int s = (int)(r >> 8);
    int p = atomicAdd(&lcnt[d0], 1);
    if (p < ELLW) ell[(size_t)(b * 256 + d0) * ELLW + p] = s;
  }
  __syncthreads();
  int node = b * 256 + t;
  if (node < N) {
    int c = lcnt[t];
    cnt[node] = c;
    float s = rsqrtf((float)(c + 1));
    dis[node] = s;
    x4[node] = make_float4(s * x[node * 3 + 0], s * x[node * 3 + 1],
                           s * x[node * 3 + 2], 0.f);
  }
}

__global__ void k_ovf_build(const int2* __restrict__ ovf, const int* __restrict__ ovfn,
                            int* cnt, int* ell, const float* __restrict__ x,
                            float* dis, float4* x4) {
  int n = *ovfn; if (n > OVF_CAP) n = OVF_CAP;
  for (int k = threadIdx.x; k < n; k += blockDim.x) {
    int2 e = ovf[k];
    int p = atomicAdd(&cnt[e.y], 1);
    if (p < ELLW) ell[(size_t)e.y * ELLW + p] = e.x;
  }
  __syncthreads();
  for (int k = threadIdx.x; k < n; k += blockDim.x) {
    int d = ovf[k].y;
    float s = rsqrtf((float)(cnt[d] + 1));
    dis[d] = s;
    x4[d] = make_float4(s * x[d * 3 + 0], s * x[d * 3 + 1], s * x[d * 3 + 2], 0.f);
  }
}

// ---------------- fallback path (N > 102400) ----------------

__global__ void k_fill_ell1(const int* __restrict__ src, const int* __restrict__ dst,
                            int* cnt, int* ell, int E) {
  int e = blockIdx.x * blockDim.x + threadIdx.x;
  if (e < E) {
    int d = dst[e];
    int p = atomicAdd(&cnt[d], 1);
    if (p < ELLW) ell[(size_t)d * ELLW + p] = src[e];
  }
}

__global__ void k_dis_prepx(const int* __restrict__ cnt, const float* __restrict__ x,
                            float* __restrict__ dis, float4* __restrict__ x4, int N) {
  int i = blockIdx.x * blockDim.x + threadIdx.x;
  if (i >= N) return;
  float s = rsqrtf((float)(cnt[i] + 1));
  dis[i] = s;
  x4[i] = make_float4(s * x[i * 3 + 0], s * x[i * 3 + 1], s * x[i * 3 + 2], 0.f);
}

// ---------------- both weights -> fp16 transposed [n][k] ----------------

__global__ void k_prep_w16x2(const float* __restrict__ W1, const float* __restrict__ W2,
                             _Float16* __restrict__ Wt1, _Float16* __restrict__ Wt2) {
  int idx = blockIdx.x * blockDim.x + threadIdx.x;
  if (idx >= 2 * HID * HID) return;
  int which = idx >> 14;
  int r = idx & (HID * HID - 1);
  int k = r >> 7, n = r & 127;
  const float* W = which ? W2 : W1;
  _Float16* Wt = which ? Wt2 : Wt1;
  Wt[n * HID + k] = (_Float16)W[r];
}

// ---------------- fused: agg (ILP-unrolled) + layer0-transform + layer1-GEMM --------
// g8a = fp8( FP8_SCALE * dis * (h0 @ W1) ), LDS-staged coalesced fp8 stores.

__global__ __launch_bounds__(256) void k_l01(
    const float4* __restrict__ x4, const int* __restrict__ ell,
    const int* __restrict__ cnt, const float* __restrict__ W0,
    const float* __restrict__ b0, const _Float16* __restrict__ wt1,
    const float* __restrict__ dis, unsigned char* __restrict__ G8, int N) {
  __shared__ _Float16 hs[64][136];   // 17408 B; reused as fp8 byte buffer in epilogue
  int t = threadIdx.x;
  int base = blockIdx.x * 64;

  {
    int r = t >> 2, sub = t & 3;
    int row = base + r;
    int rc = (row < N) ? row : (N - 1);

    // aggregate quarter of the edge list; unrolled with independent loads
    float ax = 0.f, ay = 0.f, az = 0.f;
    int c = cnt[rc]; if (c > ELLW) c = ELLW;
    const int* er = ell + (size_t)rc * ELLW;
    int k = sub;
    for (; k + 12 < c; k += 16) {
      int i0 = er[k], i1 = er[k + 4], i2 = er[k + 8], i3 = er[k + 12];
      float4 v0 = x4[i0], v1 = x4[i1], v2 = x4[i2], v3 = x4[i3];
      ax += (v0.x + v1.x) + (v2.x + v3.x);
      ay += (v0.y + v1.y) + (v2.y + v3.y);
      az += (v0.z + v1.z) + (v2.z + v3.z);
    }
    for (; k + 4 < c; k += 8) {
      int i0 = er[k], i1 = er[k + 4];
      float4 v0 = x4[i0], v1 = x4[i1];
      ax += v0.x + v1.x; ay += v0.y + v1.y; az += v0.z + v1.z;
    }
    if (k < c) {
      float4 v = x4[er[k]];
      ax += v.x; ay += v.y; az += v.z;
    }
    if (sub == 0) {  // self-loop
      float4 v = x4[rc];
      ax += v.x; ay += v.y; az += v.z;
    }
    ax += __shfl_xor(ax, 1); ax += __shfl_xor(ax, 2);
    ay += __shfl_xor(ay, 1); ay += __shfl_xor(ay, 2);
    az += __shfl_xor(az, 1); az += __shfl_xor(az, 2);
    float s = dis[rc];
    float zx = s * ax, zy = s * ay, zz = s * az;

    int c0 = sub * 32;
#pragma unroll
    for (int cdx = 0; cdx < 32; cdx += 4) {
      int cc = c0 + cdx;
      float4 w0 = *(const float4*)&W0[0 * HID + cc];
      float4 w1 = *(const float4*)&W0[1 * HID + cc];
      float4 w2 = *(const float4*)&W0[2 * HID + cc];
      float4 bb = *(const float4*)&b0[cc];
      H4v o;
      o.x = (_Float16)fmaxf(zx * w0.x + zy * w1.x + zz * w2.x + bb.x, 0.f);
      o.y = (_Float16)fmaxf(zx * w0.y + zy * w1.y + zz * w2.y + bb.y, 0.f);
      o.z = (_Float16)fmaxf(zx * w0.z + zy * w1.z + zz * w2.z + bb.z, 0.f);
      o.w = (_Float16)fmaxf(zx * w0.w + zy * w1.w + zz * w2.w + bb.w, 0.f);
      *(H4v*)&hs[r][cc] = o;
    }
  }
  __syncthreads();

  int w = t >> 6, lane = t & 63;
  int kg = lane >> 4, ccol = lane & 15;
  int lrow = w * 16 + ccol;

  f32x4 acc[8];
#pragma unroll
  for (int nt = 0; nt < 8; ++nt) acc[nt] = (f32x4){0.f, 0.f, 0.f, 0.f};

#pragma unroll
  for (int kt = 0; kt < 4; ++kt) {
    half8 a = *(const half8*)&hs[lrow][kg * 8 + kt * 32];
#pragma unroll
    for (int nt = 0; nt < 8; ++nt) {
      half8 b = *(const half8*)(wt1 + (size_t)(nt * 16 + ccol) * HID + kg * 8 + kt * 32);
      acc[nt] = __builtin_amdgcn_mfma_f32_16x16x32_f16(a, b, acc[nt], 0, 0, 0);
    }
  }
  __syncthreads();  // MFMA reads of hs complete; safe to overwrite as byte buffer

  unsigned char* bytebuf = (unsigned char*)&hs[0][0];  // 64*144 = 9216 B
#pragma unroll
  for (int j = 0; j < 4; ++j) {
    int rl = w * 16 + kg * 4 + j;
    int row = base + rl;
    float s = dis[(row < N) ? row : (N - 1)] * FP8_SCALE;
#pragma unroll
    for (int nt = 0; nt < 8; ++nt) {
      bytebuf[rl * 144 + nt * 16 + ccol] = f32_to_fp8(s * acc[nt][j]);
    }
  }
  __syncthreads();

#pragma unroll
  for (int half = 0; half < 2; ++half) {
    int rl = (t >> 3) + half * 32;
    int seg = t & 7;
    int row = base + rl;
    if (row < N) {
      uint4 v = *(const uint4*)&bytebuf[rl * 144 + seg * 16];
      *(uint4*)&G8[(size_t)row * HID + seg * 16] = v;
    }
  }
}

// ---------------- layer-1 gather (fp8 payload, 16 lanes/row x 8B) ----------------

__global__ __launch_bounds__(256) void k_g1(
    const unsigned char* __restrict__ g8, const int* __restrict__ ell,
    const int* __restrict__ cnt, const float* __restrict__ dis,
    const float* __restrict__ b, unsigned char* __restrict__ q8, int N) {
  int tid = blockIdx.x * blockDim.x + threadIdx.x;
  int i = tid >> 4;
  int q = tid & 15;
  if (i >= N) return;
  const unsigned char* gq = g8 + q * 8;

  float acc[8];
  fp8x8_to_f32(*(const uint2*)(gq + (size_t)i * HID), acc);   // self-loop

  int c = cnt[i]; if (c > ELLW) c = ELLW;
  const int* row = ell + (size_t)i * ELLW;
  int k = 0;
  for (; k + 4 <= c; k += 4) {
    int4 s4 = *(const int4*)(row + k);
    uint2 u0 = *(const uint2*)(gq + (size_t)s4.x * HID);
    uint2 u1 = *(const uint2*)(gq + (size_t)s4.y * HID);
    uint2 u2 = *(const uint2*)(gq + (size_t)s4.z * HID);
    uint2 u3 = *(const uint2*)(gq + (size_t)s4.w * HID);
    fp8x8_add(u0, acc);
    fp8x8_add(u1, acc);
    fp8x8_add(u2, acc);
    fp8x8_add(u3, acc);
  }
  for (; k < c; ++k) {
    fp8x8_add(*(const uint2*)(gq + (size_t)row[k] * HID), acc);
  }

  float sc = dis[i];
  float sc_in = sc * FP8_INV;
  float sc_out = sc * FP8_SCALE;
  float o[8];
#pragma unroll
  for (int j = 0; j < 8; ++j) {
    float bb = b[q * 8 + j];
    o[j] = sc_out * fmaxf(sc_in * acc[j] + bb, 0.f);
  }
  int w0 = __builtin_amdgcn_cvt_pk_fp8_f32(o[0], o[1], 0, false);
  w0 = __builtin_amdgcn_cvt_pk_fp8_f32(o[2], o[3], w0, true);
  int w1 = __builtin_amdgcn_cvt_pk_fp8_f32(o[4], o[5], 0, false);
  w1 = __builtin_amdgcn_cvt_pk_fp8_f32(o[6], o[7], w1, true);
  uint2 ov; ov.x = (unsigned)w0; ov.y = (unsigned)w1;
  *(uint2*)(q8 + (size_t)i * HID + q * 8) = ov;
}

// ---------------- final: gather(q8) -> v=dis*agg -> MFMA W2 -> relu+b2 -> pool ------

__global__ __launch_bounds__(256) void k_gpool2(
    const unsigned char* __restrict__ q8, const int* __restrict__ ell,
    const int* __restrict__ cnt, const float* __restrict__ dis,
    const float* __restrict__ b2, const _Float16* __restrict__ wt2,
    const int* __restrict__ batch, float* __restrict__ pool, int N) {
  __shared__ _Float16 hs[16][136];
  int t = threadIdx.x;
  int base = blockIdx.x * 16;
  int gi = t >> 4, q = t & 15;
  int i = base + gi;

  if (i < N) {
    const unsigned char* gq = q8 + q * 8;
    float acc[8];
    fp8x8_to_f32(*(const uint2*)(gq + (size_t)i * HID), acc);

    int c = cnt[i]; if (c > ELLW) c = ELLW;
    const int* row = ell + (size_t)i * ELLW;
    int k = 0;
    for (; k + 4 <= c; k += 4) {
      int4 s4 = *(const int4*)(row + k);
      uint2 u0 = *(const uint2*)(gq + (size_t)s4.x * HID);
      uint2 u1 = *(const uint2*)(gq + (size_t)s4.y * HID);
      uint2 u2 = *(const uint2*)(gq + (size_t)s4.z * HID);
      uint2 u3 = *(const uint2*)(gq + (size_t)s4.w * HID);
      fp8x8_add(u0, acc);
      fp8x8_add(u1, acc);
      fp8x8_add(u2, acc);
      fp8x8_add(u3, acc);
    }
    for (; k < c; ++k) {
      fp8x8_add(*(const uint2*)(gq + (size_t)row[k] * HID), acc);
    }

    float sc = dis[i] * FP8_INV;
    half8 o;
#pragma unroll
    for (int j = 0; j < 8; ++j) o[j] = (_Float16)(sc * acc[j]);
    *(half8*)&hs[gi][q * 8] = o;
  } else {
    half8 zo;
#pragma unroll
    for (int j = 0; j < 8; ++j) zo[j] = (_Float16)0.f;
    *(half8*)&hs[gi][q * 8] = zo;
  }
  __syncthreads();

  int w = t >> 6, lane = t & 63;
  int kg = lane >> 4, rloc = lane & 15;
  f32x4 acc2[2];
  acc2[0] = (f32x4){0.f, 0.f, 0.f, 0.f};
  acc2[1] = (f32x4){0.f, 0.f, 0.f, 0.f};

#pragma unroll
  for (int kt = 0; kt < 4; ++kt) {
    half8 a = *(const half8*)&hs[rloc][kg * 8 + kt * 32];
#pragma unroll
    for (int ntl = 0; ntl < 2; ++ntl) {
      int n = (2 * w + ntl) * 16 + rloc;
      half8 bf = *(const half8*)(wt2 + (size_t)n * HID + kg * 8 + kt * 32);
      acc2[ntl] = __builtin_amdgcn_mfma_f32_16x16x32_f16(a, bf, acc2[ntl], 0, 0, 0);
    }
  }

  float v2[2][4];
#pragma unroll
  for (int ntl = 0; ntl < 2; ++ntl) {
    int col = (2 * w + ntl) * 16 + rloc;
    float bb = b2[col];
#pragma unroll
    for (int j = 0; j < 4; ++j) v2[ntl][j] = fmaxf(acc2[ntl][j] + bb, 0.f);
  }
  int brow[4];
#pragma unroll
  for (int j = 0; j < 4; ++j) {
    int row = base + kg * 4 + j;
    brow[j] = (row < N) ? batch[row] : -1;
  }
  int g0 = batch[base];
  int lastr = base + 15; if (lastr >= N) lastr = N - 1;
  int g1 = batch[lastr];

  for (int s = g0; s <= g1; ++s) {
#pragma unroll
    for (int ntl = 0; ntl < 2; ++ntl) {
      float p = 0.f;
#pragma unroll
      for (int j = 0; j < 4; ++j) p += (brow[j] == s) ? v2[ntl][j] : 0.f;
      p += __shfl_xor(p, 16);
      p += __shfl_xor(p, 32);
      if (kg == 0 && p != 0.f) {
        atomicAdd(&pool[s * HID + (2 * w + ntl) * 16 + rloc], p);
      }
    }
  }
}

// ---------------- MLP head ----------------

__device__ __forceinline__ int lower_bound_i(const int* __restrict__ a, int n, int v) {
  int lo = 0, hi = n;
  while (lo < hi) {
    int m = (lo + hi) >> 1;
    if (a[m] < v) lo = m + 1; else hi = m;
  }
  return lo;
}

__global__ __launch_bounds__(64) void k_mlp512(
    const float* __restrict__ pool, const int* __restrict__ batch, int N,
    const float* __restrict__ Wf1, const float* __restrict__ bf1,
    const float* __restrict__ Wf2, const float* __restrict__ bf2,
    float* __restrict__ out) {
  int g = blockIdx.x;
  int lane = threadIdx.x;
  int lo = lower_bound_i(batch, N, g);
  int hi = lower_bound_i(batch, N, g + 1);
  float inv = 1.0f / fmaxf((float)(hi - lo), 1.0f);

  __shared__ float p[128];
  p[lane] = pool[g * HID + lane] * inv;
  p[lane + 64] = pool[g * HID + 64 + lane] * inv;
  __syncthreads();

  float a = bf1[lane];
  for (int k = 0; k < 128; ++k) a += p[k] * Wf1[k * 64 + lane];
  a = fmaxf(a, 0.f);
  float prod = a * Wf2[lane];
#pragma unroll
  for (int off = 32; off; off >>= 1) prod += __shfl_down(prod, off);
  if (lane == 0) out[g] = prod + bf2[0];
}

// ---------------- launch ----------------

static inline size_t align256(size_t x) { return (x + 255) & ~(size_t)255; }

extern "C" void kernel_launch(void* const* d_in, const int* in_sizes, int n_in,
                              void* d_out, int out_size, void* d_ws, size_t ws_size,
                              hipStream_t stream) {
  const float* x = (const float*)d_in[0];
  const int* ei = (const int*)d_in[1];
  const int* batch = (const int*)d_in[2];
  const float* W0 = (const float*)d_in[3];
  const float* b0 = (const float*)d_in[4];
  const float* W1 = (const float*)d_in[5];
  const float* b1 = (const float*)d_in[6];
  const float* W2 = (const float*)d_in[7];
  const float* b2 = (const float*)d_in[8];
  const float* Wf1 = (const float*)d_in[9];
  const float* bf1 = (const float*)d_in[10];
  const float* Wf2 = (const float*)d_in[11];
  const float* bf2 = (const float*)d_in[12];
  float* out = (float*)d_out;

  const int N = in_sizes[0] / 3;
  const int E = in_sizes[1] / 2;
  const int Gn = out_size;
  const int nbuk = (N + 255) >> 8;

  const int* src = ei;
  const int* dst = ei + E;

  char* ws = (char*)d_ws;
  size_t o = 0;
  int* cnt = (int*)(ws + o); o = align256(o + (size_t)N * 4);
  float* dis = (float*)(ws + o); o = align256(o + (size_t)N * 4);
  float4* x4 = (float4*)(ws + o); o = align256(o + (size_t)N * 16);
  int* ell = (int*)(ws + o); o = align256(o + (size_t)N * ELLW * 4);
  unsigned char* g8a = (unsigned char*)(ws + o); o = align256(o + (size_t)N * HID);
  unsigned char* q8 = (unsigned char*)(ws + o); o = align256(o + (size_t)N * HID);
  _Float16* wt1 = (_Float16*)(ws + o); o = align256(o + (size_t)HID * HID * 2);
  _Float16* wt2 = (_Float16*)(ws + o); o = align256(o + (size_t)HID * HID * 2);
  // bkcnt(+ovfn) and pool adjacent -> single zeroing launch covers both
  size_t zero_base = o;
  int* bkcnt = (int*)(ws + o); o = align256(o + (size_t)(NBINS + 1) * 4);
  int* ovfn = bkcnt + NBINS;
  float* pool = (float*)(ws + o); o = align256(o + (size_t)Gn * HID * 4);
  size_t zero_bytes = o - zero_base;
  unsigned* bk = (unsigned*)(ws + o); o = align256(o + (size_t)NBINS * BKCAP * 4);
  int2* ovf = (int2*)(ws + o); o = align256(o + (size_t)OVF_CAP * 8);

  const int BS = 256;
  int gN = (N + BS - 1) / BS;
  int gN16 = (int)(((long long)N * 16 + BS - 1) / BS);
  int gW2 = (2 * HID * HID + BS - 1) / BS;
  int zn = (int)(zero_bytes / 4);

  // ---- zero bkcnt + ovfn + pool in one launch ----
  k_zero_ints<<<(zn + BS - 1) / BS, BS, 0, stream>>>((int*)(ws + zero_base), zn);

  // ---- ELL build (+ dis + x4) ----
  bool vec4ok = (E % 4 == 0) && (((uintptr_t)src & 15) == 0) && (((uintptr_t)dst & 15) == 0);
  if (nbuk <= NBINS) {
    int E4 = E / 4;
    if (E4 > 0 && vec4ok) {
      k_binA<<<(E4 + CHUNK_I4 - 1) / CHUNK_I4, 256, 0, stream>>>(
          (const int4*)src, (const int4*)dst, E4, bkcnt, bk, ovfn, ovf);
      if (E % 4) k_tail_ovf<<<1, 64, 0, stream>>>(src, dst, E4 * 4, E, ovfn, ovf);
    } else {
      k_tail_ovf<<<1, 256, 0, stream>>>(src, dst, 0, E, ovfn, ovf);
    }
    k_ell_build2<<<nbuk, 256, 0, stream>>>(bk, bkcnt, ell, cnt, x, dis, x4, N);
    k_ovf_build<<<1, 256, 0, stream>>>(ovf, ovfn, cnt, ell, x, dis, x4);
  } else {
    k_zero_ints<<<gN, BS, 0, stream>>>(cnt, N);
    k_fill_ell1<<<(E + BS - 1) / BS, BS, 0, stream>>>(src, dst, cnt, ell, E);
    k_dis_prepx<<<gN, BS, 0, stream>>>(cnt, x, dis, x4, N);
  }

  // ---- weight prep ----
  k_prep_w16x2<<<gW2, BS, 0, stream>>>(W1, W2, wt1, wt2);

  // ---- fused: agg (ILP) + h0 = relu(z@W0+b0) + g8a = fp8(dis*(h0@W1)) ----
  k_l01<<<(N + 63) / 64, 256, 0, stream>>>(x4, ell, cnt, W0, b0, wt1, dis, g8a, N);

  // ---- gather: q8 = fp8(dis * relu(dis * (A g8a) + b1)) ----
  k_g1<<<gN16, BS, 0, stream>>>(g8a, ell, cnt, dis, b1, q8, N);

  // ---- final: gather(q8) -> v -> @W2 + b2, relu -> pool ----
  k_gpool2<<<(N + 15) / 16, 256, 0, stream>>>(q8, ell, cnt, dis, b2, wt2, batch, pool, N);

  // ---- MLP head ----
  k_mlp512<<<Gn, 64, 0, stream>>>(pool, batch, N, Wf1, bf1, Wf2, bf2, out);
}